// Round 1
// baseline (484.664 us; speedup 1.0000x reference)
//
#include <hip/hip_runtime.h>
#include <hip/hip_bf16.h>
#include <stdint.h>

// BitNet-style quantized FFN for MI355X (gfx950).
// Pipeline: absmax(w1,w2) -> scales -> wquant -> LN+actquant ->
//           i8 GEMM1 (+dequant+bias+swish, bf16 out) -> actquant(h) ->
//           i8 GEMM2 (+dequant+bias+mask+residual, fp32 out)
// R5: GEMMs rewritten to the 256x256 8-wave phase-split schedule (T3+T4+T5):
//     512 thr, 2M x 4N waves, wave tile 128x64 (4x2 frags of 32x32x32 i8),
//     double-buffered 128KB LDS, raw s_barrier per phase (no vmcnt drain),
//     one s_waitcnt vmcnt(0) per K-tile, setprio(1) around MFMA cluster,
//     bijective XCD swizzle. Replaces the single-buffered __syncthreads
//     structure (24% MfmaUtil ceiling).
// NB: SQ_LDS_BANK_CONFLICT == 8 cyc x staging-instr count (artifact of
//     global_load_lds write occupancy), not read conflicts.

typedef int v4i __attribute__((ext_vector_type(4)));
typedef int v16i __attribute__((ext_vector_type(16)));

__device__ __forceinline__ float wave_max64(float v) {
#pragma unroll
  for (int off = 32; off; off >>= 1) v = fmaxf(v, __shfl_xor(v, off, 64));
  return v;
}

__device__ __forceinline__ void load16_to_lds(const int8_t* g, int8_t* l) {
  __builtin_amdgcn_global_load_lds((const __attribute__((address_space(1))) void*)g,
                                   (__attribute__((address_space(3))) void*)l, 16, 0, 0);
}

// ---------------- per-tensor weight absmax ----------------
__global__ __launch_bounds__(256) void absmax_kernel(const float* __restrict__ w, int n4,
                                                     int* __restrict__ slot) {
  float m = 0.f;
  const float4* w4 = (const float4*)w;
  for (int i = blockIdx.x * 256 + threadIdx.x; i < n4; i += gridDim.x * 256) {
    float4 v = w4[i];
    m = fmaxf(fmaxf(fabsf(v.x), fabsf(v.y)), fmaxf(fmaxf(fabsf(v.z), fabsf(v.w)), m));
  }
  m = wave_max64(m);
  __shared__ float sm[4];
  int lane = threadIdx.x & 63, wv = threadIdx.x >> 6;
  if (!lane) sm[wv] = m;
  __syncthreads();
  if (!threadIdx.x) {
    m = fmaxf(fmaxf(sm[0], sm[1]), fmaxf(sm[2], sm[3]));
    atomicMax(slot, __float_as_int(m));  // nonneg float bits are int-monotone
  }
}

// ---------------- scales ----------------
__global__ void scales_kernel(const int* __restrict__ wmax, const int* __restrict__ bits,
                              float* __restrict__ scal) {
  float qb = (float)((1 << (bits[0] - 1)) - 1);
  scal[2] = qb / fmaxf(__int_as_float(wmax[0]), 1e-5f);
  scal[3] = qb / fmaxf(__int_as_float(wmax[1]), 1e-5f);
  scal[4] = qb;
}

// ---------------- weight quantization to int8 ----------------
__global__ __launch_bounds__(256) void wquant_kernel(const float* __restrict__ w,
                                                     const float* __restrict__ scal, int which,
                                                     int8_t* __restrict__ out) {
  float s = scal[2 + which], qb = scal[4];
  int i = blockIdx.x * 256 + threadIdx.x;
  float4 v = ((const float4*)w)[i];
  char4 q;
  q.x = (char)(int)rintf(fminf(fmaxf(v.x * s, -qb), qb));
  q.y = (char)(int)rintf(fminf(fmaxf(v.y * s, -qb), qb));
  q.z = (char)(int)rintf(fminf(fmaxf(v.z * s, -qb), qb));
  q.w = (char)(int)rintf(fminf(fmaxf(v.w * s, -qb), qb));
  ((char4*)out)[i] = q;
}

// ---------------- fused LayerNorm + per-row int8 absmax quant ----------------
__global__ __launch_bounds__(256) void ln_quant_kernel(const float* __restrict__ x,
                                                       const float* __restrict__ gamma,
                                                       const float* __restrict__ beta,
                                                       int8_t* __restrict__ xq,
                                                       float* __restrict__ xscale) {
  const int row = blockIdx.x;            // 16384 rows, D=1024
  const int tid = threadIdx.x;           // 256 threads x 4 elems
  const float4 v = ((const float4*)(x + (size_t)row * 1024))[tid];
  float s = v.x + v.y + v.z + v.w;
  float ss = fmaf(v.x, v.x, fmaf(v.y, v.y, fmaf(v.z, v.z, v.w * v.w)));
#pragma unroll
  for (int off = 32; off; off >>= 1) {
    s += __shfl_xor(s, off, 64);
    ss += __shfl_xor(ss, off, 64);
  }
  __shared__ float sm[8];
  const int lane = tid & 63, wv = tid >> 6;
  if (!lane) { sm[wv] = s; sm[4 + wv] = ss; }
  __syncthreads();
  s = sm[0] + sm[1] + sm[2] + sm[3];
  ss = sm[4] + sm[5] + sm[6] + sm[7];
  const float mu = s * (1.f / 1024.f);
  const float var = ss * (1.f / 1024.f) - mu * mu;
  const float rstd = rsqrtf(var + 1e-5f);
  const float4 g = ((const float4*)gamma)[tid];
  const float4 bb = ((const float4*)beta)[tid];
  float y0 = (v.x - mu) * rstd * g.x + bb.x;
  float y1 = (v.y - mu) * rstd * g.y + bb.y;
  float y2 = (v.z - mu) * rstd * g.z + bb.z;
  float y3 = (v.w - mu) * rstd * g.w + bb.w;
  float am = fmaxf(fmaxf(fabsf(y0), fabsf(y1)), fmaxf(fabsf(y2), fabsf(y3)));
  am = wave_max64(am);
  __syncthreads();
  if (!lane) sm[wv] = am;
  __syncthreads();
  am = fmaxf(fmaxf(sm[0], sm[1]), fmaxf(sm[2], sm[3]));
  const float scale = 127.f / fmaxf(am, 1e-5f);
  char4 q;
  q.x = (char)(int)rintf(fminf(fmaxf(y0 * scale, -127.f), 127.f));
  q.y = (char)(int)rintf(fminf(fmaxf(y1 * scale, -127.f), 127.f));
  q.z = (char)(int)rintf(fminf(fmaxf(y2 * scale, -127.f), 127.f));
  q.w = (char)(int)rintf(fminf(fmaxf(y3 * scale, -127.f), 127.f));
  ((char4*)(xq + (size_t)row * 1024))[tid] = q;
  if (!tid) xscale[row] = scale;
}

// ---------------- per-row int8 absmax quant of bf16 h [16384,4096] ----------------
__global__ __launch_bounds__(256) void hquant_kernel(const ushort* __restrict__ h,
                                                     int8_t* __restrict__ hq,
                                                     float* __restrict__ hscale) {
  const int row = blockIdx.x;
  const int tid = threadIdx.x;           // 256 threads x 16 elems
  const int4* p = (const int4*)(h + (size_t)row * 4096);
  union { int4 i4; ushort u[8]; } ua, ub;
  ua.i4 = p[tid * 2];
  ub.i4 = p[tid * 2 + 1];
  float f[16];
#pragma unroll
  for (int i = 0; i < 8; ++i) f[i] = __uint_as_float((unsigned)ua.u[i] << 16);
#pragma unroll
  for (int i = 0; i < 8; ++i) f[8 + i] = __uint_as_float((unsigned)ub.u[i] << 16);
  float am = 0.f;
#pragma unroll
  for (int i = 0; i < 16; ++i) am = fmaxf(am, fabsf(f[i]));
  am = wave_max64(am);
  __shared__ float sm[4];
  const int lane = tid & 63, wv = tid >> 6;
  if (!lane) sm[wv] = am;
  __syncthreads();
  am = fmaxf(fmaxf(sm[0], sm[1]), fmaxf(sm[2], sm[3]));
  const float scale = 127.f / fmaxf(am, 1e-5f);
  union { int4 i4; char c[16]; } q;
#pragma unroll
  for (int i = 0; i < 16; ++i)
    q.c[i] = (char)(int)rintf(fminf(fmaxf(f[i] * scale, -127.f), 127.f));
  ((int4*)(hq + (size_t)row * 4096))[tid] = q.i4;
  if (!tid) hscale[row] = scale;
}

// ---------------- i8 MFMA GEMM core: 256x256 tile, 8-wave phase-split ----------------
// 8 waves tiled 2(M) x 4(N); wave tile 128x64 = 4x2 frags of 32x32x32.
// LDS: double-buffered A,B tiles of 256x128B each (128KB total). 128-B rows;
// k-chunk c of row r stored at physical slot c^(r&7) (swizzle applied at
// global-fetch addressing; global_load_lds dest is wave-uniform base+lane*16).
// Per K-tile: 4 phases of {issue 2 prefetch gload_lds -> next buf | 6x
// ds_read_b128 | raw s_barrier | setprio(1) 8x MFMA setprio(0) | raw
// s_barrier}; single s_waitcnt vmcnt(0) per K-tile (loads stay in flight
// across phase barriers -- counted-vmcnt discipline, T3+T4).
template <int K>
__device__ __forceinline__ void gemm_core8(const int8_t* __restrict__ A,
                                           const int8_t* __restrict__ B, int8_t* As, int8_t* Bs,
                                           v16i (&acc)[4][2], int mIdx, int nIdx) {
  const int tid = threadIdx.x;
  const int lane = tid & 63;
  const int wave = tid >> 6;
  const int wm = (wave & 1) * 128;
  const int wn = (wave >> 1) * 64;
  const int lrow = lane & 31;
  const int half = lane >> 5;
  const int x7 = lrow & 7;
  const size_t m0 = (size_t)mIdx * 256;
  const size_t n0 = (size_t)nIdx * 256;

  // staging: thread handles 16B chunk (tid + p*512) per buffer side;
  // row r = tid>>3 (+64 per p, preserves r&7), swizzled k-offset cs
  const int r = tid >> 3;
  const int cs = ((tid & 7) ^ (r & 7)) << 4;
  const int8_t* ga = A + (m0 + r) * K + cs;
  const int8_t* gb = B + (n0 + r) * K + cs;
  int8_t* la = As + tid * 16;
  int8_t* lb = Bs + tid * 16;

  constexpr int NT = K / 128;

  // prologue: stage K-tile 0 into buffer 0
#pragma unroll
  for (int p = 0; p < 4; ++p) {
    load16_to_lds(ga + (size_t)(p * 64) * K, la + p * 8192);
    load16_to_lds(gb + (size_t)(p * 64) * K, lb + p * 8192);
  }
  asm volatile("s_waitcnt vmcnt(0)" ::: "memory");
  __builtin_amdgcn_sched_barrier(0);
  __builtin_amdgcn_s_barrier();

  for (int kt = 0; kt < NT; ++kt) {
    const int buf = kt & 1;
    const int8_t* Ab = As + buf * 32768;
    const int8_t* Bb = Bs + buf * 32768;
    int8_t* lan = la + (buf ^ 1) * 32768;
    int8_t* lbn = lb + (buf ^ 1) * 32768;
    const size_t knext = (size_t)(kt + 1) * 128;
    const bool pf = (kt + 1 < NT);
#pragma unroll
    for (int p = 0; p < 4; ++p) {
      // issue this phase's slice of next-tile prefetch (stays in flight
      // across the phase barriers below; drained once at tile end)
      if (pf) {
        load16_to_lds(ga + (size_t)(p * 64) * K + knext, lan + p * 8192);
        load16_to_lds(gb + (size_t)(p * 64) * K + knext, lbn + p * 8192);
      }
      // register fragments for k-slice p of current buffer
      const int so = ((p * 2 + half) ^ x7) << 4;
      v4i af[4], bf[2];
#pragma unroll
      for (int i = 0; i < 4; ++i)
        af[i] = *(const v4i*)(Ab + (wm + i * 32 + lrow) * 128 + so);
#pragma unroll
      for (int j = 0; j < 2; ++j)
        bf[j] = *(const v4i*)(Bb + (wn + j * 32 + lrow) * 128 + so);
      __builtin_amdgcn_s_barrier();
      __builtin_amdgcn_s_setprio(1);
#pragma unroll
      for (int i = 0; i < 4; ++i)
#pragma unroll
        for (int j = 0; j < 2; ++j)
          acc[i][j] = __builtin_amdgcn_mfma_i32_32x32x32_i8(af[i], bf[j], acc[i][j], 0, 0, 0);
      __builtin_amdgcn_s_setprio(0);
      if (p == 3) {
        // tile end: next buffer must be fully staged before any wave's
        // phase-0 ds_read of it (per-wave vmcnt covers own chunks; barrier
        // covers the rest)
        if (pf) asm volatile("s_waitcnt vmcnt(0)" ::: "memory");
        __builtin_amdgcn_sched_barrier(0);
      }
      __builtin_amdgcn_s_barrier();
    }
  }
}

// ---------------- GEMM1: C=xq@w1q^T, dequant+bias+swish -> bf16 h ----------------
__global__ __launch_bounds__(512, 2) void gemm1_kernel(const int8_t* __restrict__ Aq,
                                                       const int8_t* __restrict__ Bq,
                                                       const float* __restrict__ xscale,
                                                       const float* __restrict__ scal,
                                                       const float* __restrict__ bias,
                                                       ushort* __restrict__ H) {
  __shared__ __align__(16) int8_t As[2 * 256 * 128];
  __shared__ __align__(16) int8_t Bs[2 * 256 * 128];
  // bijective XCD swizzle: nwg=1024, 128 consecutive logical tiles per XCD
  // (n-fastest: whole w1q panel L2-resident per XCD)
  const int bid = blockIdx.x;
  const int logical = (bid & 7) * 128 + (bid >> 3);
  const int mIdx = logical >> 4;   // 64 m-tiles
  const int nIdx = logical & 15;   // 16 n-tiles
  v16i acc[4][2] = {};
  gemm_core8<1024>(Aq, Bq, As, Bs, acc, mIdx, nIdx);
  const float sw1 = scal[2];
  const int lane = threadIdx.x & 63;
  const int wave = threadIdx.x >> 6;
  const int m0 = mIdx * 256 + (wave & 1) * 128;
  const int n0 = nIdx * 256 + (wave >> 1) * 64;
  const int cn = lane & 31;
  const int h4 = (lane >> 5) << 2;
#pragma unroll
  for (int i = 0; i < 4; ++i) {
#pragma unroll
    for (int reg = 0; reg < 16; ++reg) {
      const int row = (reg & 3) + ((reg >> 2) << 3) + h4;  // C/D layout (m74/m101)
      const int m = m0 + i * 32 + row;
      const float rcp = 1.0f / (xscale[m] * sw1);
#pragma unroll
      for (int j = 0; j < 2; ++j) {
        const int n = n0 + j * 32 + cn;
        const float v = (float)acc[i][j][reg] * rcp + bias[n];
        const float hsw = v / (1.0f + __expf(-v));  // swish
        __hip_bfloat16 hb = __float2bfloat16(hsw);
        H[(size_t)m * 4096 + n] = *(const ushort*)&hb;
      }
    }
  }
}

// ---------------- GEMM2: C=hq@w2q^T, dequant+bias+mask+residual -> fp32 out ----------------
__global__ __launch_bounds__(512, 2) void gemm2_kernel(const int8_t* __restrict__ Aq,
                                                       const int8_t* __restrict__ Bq,
                                                       const float* __restrict__ hscale,
                                                       const float* __restrict__ scal,
                                                       const float* __restrict__ bias,
                                                       const float* __restrict__ x,
                                                       const float* __restrict__ mask,
                                                       float* __restrict__ out) {
  __shared__ __align__(16) int8_t As[2 * 256 * 128];
  __shared__ __align__(16) int8_t Bs[2 * 256 * 128];
  // bijective XCD swizzle: nwg=256, 32 logical tiles per XCD
  const int bid = blockIdx.x;
  const int logical = (bid & 7) * 32 + (bid >> 3);
  const int mIdx = logical >> 2;   // 64 m-tiles
  const int nIdx = logical & 3;    // 4 n-tiles
  v16i acc[4][2] = {};
  gemm_core8<4096>(Aq, Bq, As, Bs, acc, mIdx, nIdx);
  const float sw2 = scal[3];
  const int lane = threadIdx.x & 63;
  const int wave = threadIdx.x >> 6;
  const int m0 = mIdx * 256 + (wave & 1) * 128;
  const int n0 = nIdx * 256 + (wave >> 1) * 64;
  const int cn = lane & 31;
  const int h4 = (lane >> 5) << 2;
#pragma unroll
  for (int i = 0; i < 4; ++i) {
#pragma unroll
    for (int reg = 0; reg < 16; ++reg) {
      const int row = (reg & 3) + ((reg >> 2) << 3) + h4;
      const int m = m0 + i * 32 + row;
      const float rcp = 1.0f / (hscale[m] * sw2);
      const float mk = 0.5f * mask[m];
#pragma unroll
      for (int j = 0; j < 2; ++j) {
        const int n = n0 + j * 32 + cn;
        const float v = (float)acc[i][j][reg] * rcp + bias[n];
        const size_t idx = (size_t)m * 1024 + n;
        out[idx] = x[idx] + mk * v;
      }
    }
  }
}

extern "C" void kernel_launch(void* const* d_in, const int* in_sizes, int n_in, void* d_out,
                              int out_size, void* d_ws, size_t ws_size, hipStream_t stream) {
  const float* x = (const float*)d_in[0];      // [8,2048,1024]
  const float* mask = (const float*)d_in[1];   // [8,2048,1]
  const float* gamma = (const float*)d_in[2];  // [1024]
  const float* beta = (const float*)d_in[3];   // [1024]
  const float* w1 = (const float*)d_in[4];     // [4096,1024]
  const float* b1 = (const float*)d_in[5];     // [4096]
  const float* w2 = (const float*)d_in[6];     // [1024,4096]
  const float* b2 = (const float*)d_in[7];     // [1024]
  const int* bits = (const int*)d_in[8];       // scalar
  float* out = (float*)d_out;

  char* ws = (char*)d_ws;
  int* wmax = (int*)ws;                              // slots [0],[1]
  float* scal = (float*)ws;                          // [2]=sw1 [3]=sw2 [4]=qb
  float* xscale = (float*)(ws + (1u << 20));         // 16384 f32
  float* hscale = (float*)(ws + (2u << 20));         // 16384 f32
  int8_t* w1q = (int8_t*)(ws + (4u << 20));          // 4 MB
  int8_t* w2q = (int8_t*)(ws + (8u << 20));          // 4 MB
  int8_t* xq = (int8_t*)(ws + (12u << 20));          // 16 MB
  int8_t* hq = (int8_t*)(ws + (28u << 20));          // 64 MB
  ushort* h = (ushort*)(ws + (size_t)(92u << 20));   // 128 MB bf16

  const int NW = 4096 * 1024;  // elements per weight matrix

  absmax_kernel<<<1024, 256, 0, stream>>>(w1, NW / 4, wmax + 0);
  absmax_kernel<<<1024, 256, 0, stream>>>(w2, NW / 4, wmax + 1);
  scales_kernel<<<1, 1, 0, stream>>>(wmax, bits, scal);
  wquant_kernel<<<NW / 1024, 256, 0, stream>>>(w1, scal, 0, w1q);
  wquant_kernel<<<NW / 1024, 256, 0, stream>>>(w2, scal, 1, w2q);
  ln_quant_kernel<<<16384, 256, 0, stream>>>(x, gamma, beta, xq, xscale);
  gemm1_kernel<<<1024, 512, 0, stream>>>(xq, w1q, xscale, scal, b1, h);
  hquant_kernel<<<16384, 256, 0, stream>>>(h, hq, hscale);
  gemm2_kernel<<<256, 512, 0, stream>>>(hq, w2q, hscale, scal, b2, x, mask, out);
}

// Round 2
// 455.105 us; speedup vs baseline: 1.0649x; 1.0649x over previous
//
#include <hip/hip_runtime.h>
#include <hip/hip_bf16.h>
#include <stdint.h>

// BitNet-style quantized FFN for MI355X (gfx950).
// Pipeline: absmax(w1,w2) -> scales -> wquant -> LN+actquant ->
//           i8 GEMM1 (+dequant+bias+swish, bf16 out) -> actquant(h) ->
//           i8 GEMM2 (+dequant+bias+mask+residual, fp32 out)
// R6: GEMM core = 256x128 block tile, BK=128B, 3-slot LDS ring (144KB),
//     TRUE counted vmcnt: tile t's 6 loads/wave are waited on two tiles
//     after issue (steady-state s_waitcnt vmcnt(12), tail 6/0) -- never
//     drains just-issued loads (T4; R5's vmcnt(0)-per-tile bug exposed a
//     full mem latency per K-tile at 1 block/CU). 8 waves 4Mx2N, wave
//     tile 64x64 = 2x2 frags of 32x32x32 i8; 2 raw s_barrier per tile;
//     setprio(1) around MFMA cluster; bijective XCD swizzle.
// NB: SQ_LDS_BANK_CONFLICT == 8 cyc x staging-instr count (artifact of
//     global_load_lds write occupancy), not read conflicts.

typedef int v4i __attribute__((ext_vector_type(4)));
typedef int v16i __attribute__((ext_vector_type(16)));

__device__ __forceinline__ float wave_max64(float v) {
#pragma unroll
  for (int off = 32; off; off >>= 1) v = fmaxf(v, __shfl_xor(v, off, 64));
  return v;
}

__device__ __forceinline__ void load16_to_lds(const int8_t* g, int8_t* l) {
  __builtin_amdgcn_global_load_lds((const __attribute__((address_space(1))) void*)g,
                                   (__attribute__((address_space(3))) void*)l, 16, 0, 0);
}

// ---------------- per-tensor weight absmax ----------------
__global__ __launch_bounds__(256) void absmax_kernel(const float* __restrict__ w, int n4,
                                                     int* __restrict__ slot) {
  float m = 0.f;
  const float4* w4 = (const float4*)w;
  for (int i = blockIdx.x * 256 + threadIdx.x; i < n4; i += gridDim.x * 256) {
    float4 v = w4[i];
    m = fmaxf(fmaxf(fabsf(v.x), fabsf(v.y)), fmaxf(fmaxf(fabsf(v.z), fabsf(v.w)), m));
  }
  m = wave_max64(m);
  __shared__ float sm[4];
  int lane = threadIdx.x & 63, wv = threadIdx.x >> 6;
  if (!lane) sm[wv] = m;
  __syncthreads();
  if (!threadIdx.x) {
    m = fmaxf(fmaxf(sm[0], sm[1]), fmaxf(sm[2], sm[3]));
    atomicMax(slot, __float_as_int(m));  // nonneg float bits are int-monotone
  }
}

// ---------------- scales ----------------
__global__ void scales_kernel(const int* __restrict__ wmax, const int* __restrict__ bits,
                              float* __restrict__ scal) {
  float qb = (float)((1 << (bits[0] - 1)) - 1);
  scal[2] = qb / fmaxf(__int_as_float(wmax[0]), 1e-5f);
  scal[3] = qb / fmaxf(__int_as_float(wmax[1]), 1e-5f);
  scal[4] = qb;
}

// ---------------- weight quantization to int8 ----------------
__global__ __launch_bounds__(256) void wquant_kernel(const float* __restrict__ w,
                                                     const float* __restrict__ scal, int which,
                                                     int8_t* __restrict__ out) {
  float s = scal[2 + which], qb = scal[4];
  int i = blockIdx.x * 256 + threadIdx.x;
  float4 v = ((const float4*)w)[i];
  char4 q;
  q.x = (char)(int)rintf(fminf(fmaxf(v.x * s, -qb), qb));
  q.y = (char)(int)rintf(fminf(fmaxf(v.y * s, -qb), qb));
  q.z = (char)(int)rintf(fminf(fmaxf(v.z * s, -qb), qb));
  q.w = (char)(int)rintf(fminf(fmaxf(v.w * s, -qb), qb));
  ((char4*)out)[i] = q;
}

// ---------------- fused LayerNorm + per-row int8 absmax quant ----------------
__global__ __launch_bounds__(256) void ln_quant_kernel(const float* __restrict__ x,
                                                       const float* __restrict__ gamma,
                                                       const float* __restrict__ beta,
                                                       int8_t* __restrict__ xq,
                                                       float* __restrict__ xscale) {
  const int row = blockIdx.x;            // 16384 rows, D=1024
  const int tid = threadIdx.x;           // 256 threads x 4 elems
  const float4 v = ((const float4*)(x + (size_t)row * 1024))[tid];
  float s = v.x + v.y + v.z + v.w;
  float ss = fmaf(v.x, v.x, fmaf(v.y, v.y, fmaf(v.z, v.z, v.w * v.w)));
#pragma unroll
  for (int off = 32; off; off >>= 1) {
    s += __shfl_xor(s, off, 64);
    ss += __shfl_xor(ss, off, 64);
  }
  __shared__ float sm[8];
  const int lane = tid & 63, wv = tid >> 6;
  if (!lane) { sm[wv] = s; sm[4 + wv] = ss; }
  __syncthreads();
  s = sm[0] + sm[1] + sm[2] + sm[3];
  ss = sm[4] + sm[5] + sm[6] + sm[7];
  const float mu = s * (1.f / 1024.f);
  const float var = ss * (1.f / 1024.f) - mu * mu;
  const float rstd = rsqrtf(var + 1e-5f);
  const float4 g = ((const float4*)gamma)[tid];
  const float4 bb = ((const float4*)beta)[tid];
  float y0 = (v.x - mu) * rstd * g.x + bb.x;
  float y1 = (v.y - mu) * rstd * g.y + bb.y;
  float y2 = (v.z - mu) * rstd * g.z + bb.z;
  float y3 = (v.w - mu) * rstd * g.w + bb.w;
  float am = fmaxf(fmaxf(fabsf(y0), fabsf(y1)), fmaxf(fabsf(y2), fabsf(y3)));
  am = wave_max64(am);
  __syncthreads();
  if (!lane) sm[wv] = am;
  __syncthreads();
  am = fmaxf(fmaxf(sm[0], sm[1]), fmaxf(sm[2], sm[3]));
  const float scale = 127.f / fmaxf(am, 1e-5f);
  char4 q;
  q.x = (char)(int)rintf(fminf(fmaxf(y0 * scale, -127.f), 127.f));
  q.y = (char)(int)rintf(fminf(fmaxf(y1 * scale, -127.f), 127.f));
  q.z = (char)(int)rintf(fminf(fmaxf(y2 * scale, -127.f), 127.f));
  q.w = (char)(int)rintf(fminf(fmaxf(y3 * scale, -127.f), 127.f));
  ((char4*)(xq + (size_t)row * 1024))[tid] = q;
  if (!tid) xscale[row] = scale;
}

// ---------------- per-row int8 absmax quant of bf16 h [16384,4096] ----------------
__global__ __launch_bounds__(256) void hquant_kernel(const ushort* __restrict__ h,
                                                     int8_t* __restrict__ hq,
                                                     float* __restrict__ hscale) {
  const int row = blockIdx.x;
  const int tid = threadIdx.x;           // 256 threads x 16 elems
  const int4* p = (const int4*)(h + (size_t)row * 4096);
  union { int4 i4; ushort u[8]; } ua, ub;
  ua.i4 = p[tid * 2];
  ub.i4 = p[tid * 2 + 1];
  float f[16];
#pragma unroll
  for (int i = 0; i < 8; ++i) f[i] = __uint_as_float((unsigned)ua.u[i] << 16);
#pragma unroll
  for (int i = 0; i < 8; ++i) f[8 + i] = __uint_as_float((unsigned)ub.u[i] << 16);
  float am = 0.f;
#pragma unroll
  for (int i = 0; i < 16; ++i) am = fmaxf(am, fabsf(f[i]));
  am = wave_max64(am);
  __shared__ float sm[4];
  const int lane = tid & 63, wv = tid >> 6;
  if (!lane) sm[wv] = am;
  __syncthreads();
  am = fmaxf(fmaxf(sm[0], sm[1]), fmaxf(sm[2], sm[3]));
  const float scale = 127.f / fmaxf(am, 1e-5f);
  union { int4 i4; char c[16]; } q;
#pragma unroll
  for (int i = 0; i < 16; ++i)
    q.c[i] = (char)(int)rintf(fminf(fmaxf(f[i] * scale, -127.f), 127.f));
  ((int4*)(hq + (size_t)row * 4096))[tid] = q.i4;
  if (!tid) hscale[row] = scale;
}

// ---------------- i8 MFMA GEMM core: 256x128 tile, 3-slot ring, counted vmcnt ----
// 8 waves 4Mx2N; wave tile 64x64 = 2x2 frags of 32x32x32 i8.
// LDS ring: 3 slots x (A 256x128B = 32KB + B 128x128B = 16KB) = 144KB.
// Per tile each wave issues 6 global_load_lds (4 A + 2 B, 1KB each).
// Steady state: at tile t issue tile t+2's loads, then s_waitcnt vmcnt(12)
// (waits ONLY tile t's loads, issued 2 tiles = ~2000cy ago); tail vmcnt(6)/
// vmcnt(0). 2 raw s_barrier per tile. LDS rows 128B; k-chunk c of row r at
// physical slot c^(r&7) (swizzle on global source addr; gload_lds dest is
// wave-uniform base + lane*16, kept linear).
template <int K>
__device__ __forceinline__ void gemm_core_r6(const int8_t* __restrict__ A,
                                             const int8_t* __restrict__ B, int8_t* smem,
                                             v16i (&acc)[2][2], int mIdx, int nIdx) {
  constexpr int NT = K / 128;
  const int tid = threadIdx.x;
  const int lane = tid & 63;
  const int wave = tid >> 6;
  const int wm = (wave & 3) * 64;
  const int wn = (wave >> 2) * 64;
  const int lrow = lane & 31;
  const int half = lane >> 5;
  const int x7 = lrow & 7;
  const size_t m0 = (size_t)mIdx * 256;
  const size_t n0 = (size_t)nIdx * 128;

  // staging: thread handles 16B chunk; row r=tid>>3 (+64 per slab, preserves
  // r&7), swizzled source k-offset cs
  const int r = tid >> 3;
  const int cs = ((tid & 7) ^ (r & 7)) << 4;
  const int8_t* ga = A + (m0 + r) * K + cs;
  const int8_t* gb = B + (n0 + r) * K + cs;

  auto stage = [&](int t, int b) {
    int8_t* la = smem + b * 49152 + tid * 16;
    int8_t* lb = smem + b * 49152 + 32768 + tid * 16;
    const size_t ko = (size_t)t * 128;
#pragma unroll
    for (int s = 0; s < 4; ++s) load16_to_lds(ga + (size_t)(s * 64) * K + ko, la + s * 8192);
#pragma unroll
    for (int s = 0; s < 2; ++s) load16_to_lds(gb + (size_t)(s * 64) * K + ko, lb + s * 8192);
  };

  auto body = [&](int b) {
    const int8_t* Ab = smem + b * 49152;
    const int8_t* Bb = Ab + 32768;
    __builtin_amdgcn_s_barrier();  // all waves' vmcnt waits done -> tile staged
    v4i af[4][2], bf[4][2];
#pragma unroll
    for (int ks = 0; ks < 4; ++ks) {
      const int so = ((ks * 2 + half) ^ x7) << 4;
#pragma unroll
      for (int i = 0; i < 2; ++i)
        af[ks][i] = *(const v4i*)(Ab + (wm + i * 32 + lrow) * 128 + so);
#pragma unroll
      for (int j = 0; j < 2; ++j)
        bf[ks][j] = *(const v4i*)(Bb + (wn + j * 32 + lrow) * 128 + so);
    }
    __builtin_amdgcn_s_setprio(1);
#pragma unroll
    for (int ks = 0; ks < 4; ++ks)
#pragma unroll
      for (int i = 0; i < 2; ++i)
#pragma unroll
        for (int j = 0; j < 2; ++j)
          acc[i][j] =
              __builtin_amdgcn_mfma_i32_32x32x32_i8(af[ks][i], bf[ks][j], acc[i][j], 0, 0, 0);
    __builtin_amdgcn_s_setprio(0);
    __builtin_amdgcn_s_barrier();  // all waves done reading slot b -> reusable
  };

  // prologue: stage tiles 0,1 (12 loads in flight)
  stage(0, 0);
  stage(1, 1);
  // steady state: issue t+2 (-> 18 in flight), wait only tile t (vmcnt 12)
#pragma unroll 3
  for (int t = 0; t < NT - 2; ++t) {
    stage(t + 2, (t + 2) % 3);
    asm volatile("s_waitcnt vmcnt(12)" ::: "memory");
    __builtin_amdgcn_sched_barrier(0);
    body(t % 3);
  }
  asm volatile("s_waitcnt vmcnt(6)" ::: "memory");
  __builtin_amdgcn_sched_barrier(0);
  body((NT - 2) % 3);
  asm volatile("s_waitcnt vmcnt(0)" ::: "memory");
  __builtin_amdgcn_sched_barrier(0);
  body((NT - 1) % 3);
}

// ---------------- GEMM1: C=xq@w1q^T, dequant+bias+swish -> bf16 h ----------------
__global__ __launch_bounds__(512, 2) void gemm1_kernel(const int8_t* __restrict__ Aq,
                                                       const int8_t* __restrict__ Bq,
                                                       const float* __restrict__ xscale,
                                                       const float* __restrict__ scal,
                                                       const float* __restrict__ bias,
                                                       ushort* __restrict__ H) {
  __shared__ __align__(16) int8_t smem[3 * 49152];  // 144 KB
  // bijective XCD swizzle: nwg=2048, 256 consecutive logical tiles per XCD
  // (n-fastest: whole w1q panel + 8 A-panels ~L2-resident per XCD)
  const int bid = blockIdx.x;
  const int logical = (bid & 7) * 256 + (bid >> 3);
  const int mIdx = logical >> 5;   // 64 m-tiles (256 rows)
  const int nIdx = logical & 31;   // 32 n-tiles (128 cols)
  v16i acc[2][2] = {};
  gemm_core_r6<1024>(Aq, Bq, smem, acc, mIdx, nIdx);
  const float sw1 = scal[2];
  const int lane = threadIdx.x & 63;
  const int wave = threadIdx.x >> 6;
  const int m0 = mIdx * 256 + (wave & 3) * 64;
  const int n0 = nIdx * 128 + (wave >> 2) * 64;
  const int cn = lane & 31;
  const int h4 = (lane >> 5) << 2;
#pragma unroll
  for (int i = 0; i < 2; ++i) {
#pragma unroll
    for (int reg = 0; reg < 16; ++reg) {
      const int row = (reg & 3) + ((reg >> 2) << 3) + h4;  // C/D layout (m74/m101)
      const int m = m0 + i * 32 + row;
      const float rcp = 1.0f / (xscale[m] * sw1);
#pragma unroll
      for (int j = 0; j < 2; ++j) {
        const int n = n0 + j * 32 + cn;
        const float v = (float)acc[i][j][reg] * rcp + bias[n];
        const float hsw = v / (1.0f + __expf(-v));  // swish
        __hip_bfloat16 hb = __float2bfloat16(hsw);
        H[(size_t)m * 4096 + n] = *(const ushort*)&hb;
      }
    }
  }
}

// ---------------- GEMM2: C=hq@w2q^T, dequant+bias+mask+residual -> fp32 out ----------------
__global__ __launch_bounds__(512, 2) void gemm2_kernel(const int8_t* __restrict__ Aq,
                                                       const int8_t* __restrict__ Bq,
                                                       const float* __restrict__ hscale,
                                                       const float* __restrict__ scal,
                                                       const float* __restrict__ bias,
                                                       const float* __restrict__ x,
                                                       const float* __restrict__ mask,
                                                       float* __restrict__ out) {
  __shared__ __align__(16) int8_t smem[3 * 49152];  // 144 KB
  // bijective XCD swizzle: nwg=512, 64 logical tiles per XCD
  const int bid = blockIdx.x;
  const int logical = (bid & 7) * 64 + (bid >> 3);
  const int mIdx = logical >> 3;   // 64 m-tiles
  const int nIdx = logical & 7;    // 8 n-tiles
  v16i acc[2][2] = {};
  gemm_core_r6<4096>(Aq, Bq, smem, acc, mIdx, nIdx);
  const float sw2 = scal[3];
  const int lane = threadIdx.x & 63;
  const int wave = threadIdx.x >> 6;
  const int m0 = mIdx * 256 + (wave & 3) * 64;
  const int n0 = nIdx * 128 + (wave >> 2) * 64;
  const int cn = lane & 31;
  const int h4 = (lane >> 5) << 2;
#pragma unroll
  for (int i = 0; i < 2; ++i) {
#pragma unroll
    for (int reg = 0; reg < 16; ++reg) {
      const int row = (reg & 3) + ((reg >> 2) << 3) + h4;
      const int m = m0 + i * 32 + row;
      const float rcp = 1.0f / (hscale[m] * sw2);
      const float mk = 0.5f * mask[m];
#pragma unroll
      for (int j = 0; j < 2; ++j) {
        const int n = n0 + j * 32 + cn;
        const float v = (float)acc[i][j][reg] * rcp + bias[n];
        const size_t idx = (size_t)m * 1024 + n;
        out[idx] = x[idx] + mk * v;
      }
    }
  }
}

extern "C" void kernel_launch(void* const* d_in, const int* in_sizes, int n_in, void* d_out,
                              int out_size, void* d_ws, size_t ws_size, hipStream_t stream) {
  const float* x = (const float*)d_in[0];      // [8,2048,1024]
  const float* mask = (const float*)d_in[1];   // [8,2048,1]
  const float* gamma = (const float*)d_in[2];  // [1024]
  const float* beta = (const float*)d_in[3];   // [1024]
  const float* w1 = (const float*)d_in[4];     // [4096,1024]
  const float* b1 = (const float*)d_in[5];     // [4096]
  const float* w2 = (const float*)d_in[6];     // [1024,4096]
  const float* b2 = (const float*)d_in[7];     // [1024]
  const int* bits = (const int*)d_in[8];       // scalar
  float* out = (float*)d_out;

  char* ws = (char*)d_ws;
  int* wmax = (int*)ws;                              // slots [0],[1]
  float* scal = (float*)ws;                          // [2]=sw1 [3]=sw2 [4]=qb
  float* xscale = (float*)(ws + (1u << 20));         // 16384 f32
  float* hscale = (float*)(ws + (2u << 20));         // 16384 f32
  int8_t* w1q = (int8_t*)(ws + (4u << 20));          // 4 MB
  int8_t* w2q = (int8_t*)(ws + (8u << 20));          // 4 MB
  int8_t* xq = (int8_t*)(ws + (12u << 20));          // 16 MB
  int8_t* hq = (int8_t*)(ws + (28u << 20));          // 64 MB
  ushort* h = (ushort*)(ws + (size_t)(92u << 20));   // 128 MB bf16

  const int NW = 4096 * 1024;  // elements per weight matrix

  absmax_kernel<<<1024, 256, 0, stream>>>(w1, NW / 4, wmax + 0);
  absmax_kernel<<<1024, 256, 0, stream>>>(w2, NW / 4, wmax + 1);
  scales_kernel<<<1, 1, 0, stream>>>(wmax, bits, scal);
  wquant_kernel<<<NW / 1024, 256, 0, stream>>>(w1, scal, 0, w1q);
  wquant_kernel<<<NW / 1024, 256, 0, stream>>>(w2, scal, 1, w2q);
  ln_quant_kernel<<<16384, 256, 0, stream>>>(x, gamma, beta, xq, xscale);
  gemm1_kernel<<<2048, 512, 0, stream>>>(xq, w1q, xscale, scal, b1, h);
  hquant_kernel<<<16384, 256, 0, stream>>>(h, hq, hscale);
  gemm2_kernel<<<512, 512, 0, stream>>>(hq, w2q, hscale, scal, b2, x, mask, out);
}

// Round 3
// 421.691 us; speedup vs baseline: 1.1493x; 1.0792x over previous
//
#include <hip/hip_runtime.h>
#include <hip/hip_bf16.h>
#include <stdint.h>

// BitNet-style quantized FFN for MI355X (gfx950).
// Pipeline: absmax(w1,w2) -> scales -> wquant -> LN+actquant ->
//           i8 GEMM1 (+dequant+bias+swish, bf16 out) -> actquant(h) ->
//           i8 GEMM2 (+dequant+bias+mask+residual, fp32 out)
// R7: GEMM core LDS-read-ratio fix. R4/R6 MfmaUtil (24%/19%) == ds_read:MFMA
//     geometry ceiling (0.75/1.0 reads per MFMA; 128 ds_read_b128 x ~8-12cy
//     of the shared LDS pipe per K-tile vs 272cy MFMA/SIMD). R7: 4 waves,
//     wave tile 128x128 = 4x4 frags of 32x32x32 i8 -> ratio 0.5 (64 reads
//     vs 272cy MFMA), acc 256 VGPR, 1 wave/SIMD, launch_bounds(256,1).
//     Block 256x256, BK=64B, ring-4 LDS slots (128KB), prefetch depth 3,
//     steady s_waitcnt vmcnt(16) (waits only loads issued 2 tiles ago),
//     one raw s_barrier/tile. Frags for tile t+1 read into alternate reg
//     set during tile t's MFMA cluster (overlap at 1 wave/SIMD).
//     XCD map: each XCD owns contiguous m-range sweeping all n -> per-XCD
//     working set = full weight panel (4MB, L2-resident) + 1 A-tile.
// NB: SQ_LDS_BANK_CONFLICT == 8 cyc x staging-instr count (artifact of
//     global_load_lds write occupancy), not read conflicts.

typedef int v4i __attribute__((ext_vector_type(4)));
typedef int v16i __attribute__((ext_vector_type(16)));

__device__ __forceinline__ float wave_max64(float v) {
#pragma unroll
  for (int off = 32; off; off >>= 1) v = fmaxf(v, __shfl_xor(v, off, 64));
  return v;
}

__device__ __forceinline__ void load16_to_lds(const int8_t* g, int8_t* l) {
  __builtin_amdgcn_global_load_lds((const __attribute__((address_space(1))) void*)g,
                                   (__attribute__((address_space(3))) void*)l, 16, 0, 0);
}

// ---------------- per-tensor weight absmax ----------------
__global__ __launch_bounds__(256) void absmax_kernel(const float* __restrict__ w, int n4,
                                                     int* __restrict__ slot) {
  float m = 0.f;
  const float4* w4 = (const float4*)w;
  for (int i = blockIdx.x * 256 + threadIdx.x; i < n4; i += gridDim.x * 256) {
    float4 v = w4[i];
    m = fmaxf(fmaxf(fabsf(v.x), fabsf(v.y)), fmaxf(fmaxf(fabsf(v.z), fabsf(v.w)), m));
  }
  m = wave_max64(m);
  __shared__ float sm[4];
  int lane = threadIdx.x & 63, wv = threadIdx.x >> 6;
  if (!lane) sm[wv] = m;
  __syncthreads();
  if (!threadIdx.x) {
    m = fmaxf(fmaxf(sm[0], sm[1]), fmaxf(sm[2], sm[3]));
    atomicMax(slot, __float_as_int(m));  // nonneg float bits are int-monotone
  }
}

// ---------------- scales ----------------
__global__ void scales_kernel(const int* __restrict__ wmax, const int* __restrict__ bits,
                              float* __restrict__ scal) {
  float qb = (float)((1 << (bits[0] - 1)) - 1);
  scal[2] = qb / fmaxf(__int_as_float(wmax[0]), 1e-5f);
  scal[3] = qb / fmaxf(__int_as_float(wmax[1]), 1e-5f);
  scal[4] = qb;
}

// ---------------- weight quantization to int8 ----------------
__global__ __launch_bounds__(256) void wquant_kernel(const float* __restrict__ w,
                                                     const float* __restrict__ scal, int which,
                                                     int8_t* __restrict__ out) {
  float s = scal[2 + which], qb = scal[4];
  int i = blockIdx.x * 256 + threadIdx.x;
  float4 v = ((const float4*)w)[i];
  char4 q;
  q.x = (char)(int)rintf(fminf(fmaxf(v.x * s, -qb), qb));
  q.y = (char)(int)rintf(fminf(fmaxf(v.y * s, -qb), qb));
  q.z = (char)(int)rintf(fminf(fmaxf(v.z * s, -qb), qb));
  q.w = (char)(int)rintf(fminf(fmaxf(v.w * s, -qb), qb));
  ((char4*)out)[i] = q;
}

// ---------------- fused LayerNorm + per-row int8 absmax quant ----------------
__global__ __launch_bounds__(256) void ln_quant_kernel(const float* __restrict__ x,
                                                       const float* __restrict__ gamma,
                                                       const float* __restrict__ beta,
                                                       int8_t* __restrict__ xq,
                                                       float* __restrict__ xscale) {
  const int row = blockIdx.x;            // 16384 rows, D=1024
  const int tid = threadIdx.x;           // 256 threads x 4 elems
  const float4 v = ((const float4*)(x + (size_t)row * 1024))[tid];
  float s = v.x + v.y + v.z + v.w;
  float ss = fmaf(v.x, v.x, fmaf(v.y, v.y, fmaf(v.z, v.z, v.w * v.w)));
#pragma unroll
  for (int off = 32; off; off >>= 1) {
    s += __shfl_xor(s, off, 64);
    ss += __shfl_xor(ss, off, 64);
  }
  __shared__ float sm[8];
  const int lane = tid & 63, wv = tid >> 6;
  if (!lane) { sm[wv] = s; sm[4 + wv] = ss; }
  __syncthreads();
  s = sm[0] + sm[1] + sm[2] + sm[3];
  ss = sm[4] + sm[5] + sm[6] + sm[7];
  const float mu = s * (1.f / 1024.f);
  const float var = ss * (1.f / 1024.f) - mu * mu;
  const float rstd = rsqrtf(var + 1e-5f);
  const float4 g = ((const float4*)gamma)[tid];
  const float4 bb = ((const float4*)beta)[tid];
  float y0 = (v.x - mu) * rstd * g.x + bb.x;
  float y1 = (v.y - mu) * rstd * g.y + bb.y;
  float y2 = (v.z - mu) * rstd * g.z + bb.z;
  float y3 = (v.w - mu) * rstd * g.w + bb.w;
  float am = fmaxf(fmaxf(fabsf(y0), fabsf(y1)), fmaxf(fabsf(y2), fabsf(y3)));
  am = wave_max64(am);
  __syncthreads();
  if (!lane) sm[wv] = am;
  __syncthreads();
  am = fmaxf(fmaxf(sm[0], sm[1]), fmaxf(sm[2], sm[3]));
  const float scale = 127.f / fmaxf(am, 1e-5f);
  char4 q;
  q.x = (char)(int)rintf(fminf(fmaxf(y0 * scale, -127.f), 127.f));
  q.y = (char)(int)rintf(fminf(fmaxf(y1 * scale, -127.f), 127.f));
  q.z = (char)(int)rintf(fminf(fmaxf(y2 * scale, -127.f), 127.f));
  q.w = (char)(int)rintf(fminf(fmaxf(y3 * scale, -127.f), 127.f));
  ((char4*)(xq + (size_t)row * 1024))[tid] = q;
  if (!tid) xscale[row] = scale;
}

// ---------------- per-row int8 absmax quant of bf16 h [16384,4096] ----------------
__global__ __launch_bounds__(256) void hquant_kernel(const ushort* __restrict__ h,
                                                     int8_t* __restrict__ hq,
                                                     float* __restrict__ hscale) {
  const int row = blockIdx.x;
  const int tid = threadIdx.x;           // 256 threads x 16 elems
  const int4* p = (const int4*)(h + (size_t)row * 4096);
  union { int4 i4; ushort u[8]; } ua, ub;
  ua.i4 = p[tid * 2];
  ub.i4 = p[tid * 2 + 1];
  float f[16];
#pragma unroll
  for (int i = 0; i < 8; ++i) f[i] = __uint_as_float((unsigned)ua.u[i] << 16);
#pragma unroll
  for (int i = 0; i < 8; ++i) f[8 + i] = __uint_as_float((unsigned)ub.u[i] << 16);
  float am = 0.f;
#pragma unroll
  for (int i = 0; i < 16; ++i) am = fmaxf(am, fabsf(f[i]));
  am = wave_max64(am);
  __shared__ float sm[4];
  const int lane = tid & 63, wv = tid >> 6;
  if (!lane) sm[wv] = am;
  __syncthreads();
  am = fmaxf(fmaxf(sm[0], sm[1]), fmaxf(sm[2], sm[3]));
  const float scale = 127.f / fmaxf(am, 1e-5f);
  union { int4 i4; char c[16]; } q;
#pragma unroll
  for (int i = 0; i < 16; ++i)
    q.c[i] = (char)(int)rintf(fminf(fmaxf(f[i] * scale, -127.f), 127.f));
  ((int4*)(hq + (size_t)row * 4096))[tid] = q.i4;
  if (!tid) hscale[row] = scale;
}

// ---------------- i8 MFMA GEMM core (R7) ----------------
// 256x256 block, 256 thr = 4 waves 2Mx2N, wave tile 128x128 = 4x4 frags of
// 32x32x32 i8 (acc 256 VGPR). BK=64B; LDS = 4 ring slots x (A 16KB + B 16KB)
// = 128KB. Each tile: 8 global_load_lds/thread (4 A + 4 B chunks), 16
// ds_read_b128/lane, 32 MFMA. Steady state: stage(t+3) issued at tile t,
// wait vmcnt(16) = only tile t+1's loads (issued 2 tiles ago) must land.
// Frags of tile t+1 read into the alternate register set while tile t's
// MFMA cluster runs. LDS chunk swizzle: phys 16B-chunk p of row r holds
// logical chunk c = p ^ ((r>>1)&3); applied on the global source address
// (gload_lds dest stays linear), inverted identically on ds_read.
template <int K>
__device__ __forceinline__ void gemm_core_r7(const int8_t* __restrict__ A,
                                             const int8_t* __restrict__ B, int8_t* smem,
                                             v16i (&acc)[4][4], int mIdx, int nIdx) {
  constexpr int NT = K / 64;           // K-tiles of 64 bytes
  const int tid = threadIdx.x;         // 256
  const int lane = tid & 63;
  const int wave = tid >> 6;           // 4 waves: 2M x 2N
  const int wm = (wave & 1) * 128;
  const int wn = (wave >> 1) * 128;
  const int lrow = lane & 31;
  const int half = lane >> 5;
  const int sw = (lrow >> 1) & 3;      // read-side chunk swizzle
  const size_t m0 = (size_t)mIdx * 256;
  const size_t n0 = (size_t)nIdx * 256;

  // staging: dest chunk index = s*256 + tid (linear LDS). row r = s*64 +
  // (tid>>2), phys chunk p = tid&3; source logical chunk c = p ^ ((r>>1)&3)
  // = (tid&3) ^ ((tid>>3)&3)  (s*64 rows -> r>>1 shifts by 32 == 0 mod 4).
  const int r0 = tid >> 2;
  const int c0 = ((tid & 3) ^ ((tid >> 3) & 3)) << 4;
  const int8_t* ga = A + (m0 + r0) * K + c0;
  const int8_t* gb = B + (n0 + r0) * K + c0;

  auto stage = [&](int t) {
    int8_t* la = smem + (t & 3) * 32768 + tid * 16;
    const size_t ko = (size_t)t * 64;
#pragma unroll
    for (int s = 0; s < 4; ++s)
      load16_to_lds(ga + (size_t)(s * 64) * K + ko, la + s * 4096);
#pragma unroll
    for (int s = 0; s < 4; ++s)
      load16_to_lds(gb + (size_t)(s * 64) * K + ko, la + 16384 + s * 4096);
  };

  auto read_frags = [&](int t, v4i (&af)[2][4], v4i (&bf)[2][4]) {
    const int8_t* Ab = smem + (t & 3) * 32768;
    const int8_t* Bb = Ab + 16384;
#pragma unroll
    for (int ks = 0; ks < 2; ++ks) {
      const int p = ((ks * 2 + half) ^ sw) << 4;
#pragma unroll
      for (int i = 0; i < 4; ++i)
        af[ks][i] = *(const v4i*)(Ab + (wm + i * 32 + lrow) * 64 + p);
#pragma unroll
      for (int j = 0; j < 4; ++j)
        bf[ks][j] = *(const v4i*)(Bb + (wn + j * 32 + lrow) * 64 + p);
    }
  };

  auto mfma_all = [&](v4i (&af)[2][4], v4i (&bf)[2][4]) {
#pragma unroll
    for (int ks = 0; ks < 2; ++ks)
#pragma unroll
      for (int i = 0; i < 4; ++i)
#pragma unroll
        for (int j = 0; j < 4; ++j)
          acc[i][j] =
              __builtin_amdgcn_mfma_i32_32x32x32_i8(af[ks][i], bf[ks][j], acc[i][j], 0, 0, 0);
  };

  v4i a0[2][4], b0[2][4], a1[2][4], b1[2][4];

  // prologue: stage tiles 0..2 (24 loads in flight); tile 0 ready at vmcnt(16)
  stage(0);
  stage(1);
  stage(2);
  asm volatile("s_waitcnt vmcnt(16)" ::: "memory");
  __builtin_amdgcn_s_barrier();
  __builtin_amdgcn_sched_barrier(0);
  read_frags(0, a0, b0);

  // main: sub-iter t does {stage t+3; wait t+1 staged; read frags t+1; mfma t}
  for (int t = 0; t < NT - 4; t += 2) {
    stage(t + 3);
    asm volatile("s_waitcnt vmcnt(16)" ::: "memory");
    __builtin_amdgcn_s_barrier();
    __builtin_amdgcn_sched_barrier(0);
    read_frags(t + 1, a1, b1);
    mfma_all(a0, b0);
    stage(t + 4);
    asm volatile("s_waitcnt vmcnt(16)" ::: "memory");
    __builtin_amdgcn_s_barrier();
    __builtin_amdgcn_sched_barrier(0);
    read_frags(t + 2, a0, b0);
    mfma_all(a1, b1);
  }
  // peeled tail: t = NT-4 (last stage), NT-3, NT-2, NT-1  (NT even)
  stage(NT - 1);
  asm volatile("s_waitcnt vmcnt(16)" ::: "memory");
  __builtin_amdgcn_s_barrier();
  __builtin_amdgcn_sched_barrier(0);
  read_frags(NT - 3, a1, b1);
  mfma_all(a0, b0);

  asm volatile("s_waitcnt vmcnt(8)" ::: "memory");
  __builtin_amdgcn_s_barrier();
  __builtin_amdgcn_sched_barrier(0);
  read_frags(NT - 2, a0, b0);
  mfma_all(a1, b1);

  asm volatile("s_waitcnt vmcnt(0)" ::: "memory");
  __builtin_amdgcn_s_barrier();
  __builtin_amdgcn_sched_barrier(0);
  read_frags(NT - 1, a1, b1);
  mfma_all(a0, b0);

  mfma_all(a1, b1);  // compiler inserts the lgkmcnt wait for the last reads
}

// ---------------- GEMM1: C=xq@w1q^T, dequant+bias+swish -> bf16 h ----------------
__global__ __launch_bounds__(256, 1) void gemm1_kernel(const int8_t* __restrict__ Aq,
                                                       const int8_t* __restrict__ Bq,
                                                       const float* __restrict__ xscale,
                                                       const float* __restrict__ scal,
                                                       const float* __restrict__ bias,
                                                       ushort* __restrict__ H) {
  __shared__ __align__(16) int8_t smem[4 * 32768];  // 128 KB
  // XCD map: xcd = bid&7 owns m-tiles [xcd*8, xcd*8+8), sweeping all 16 n
  // per m-tile -> per-XCD hot set = w1q (4MB, == L2) + 1 A-tile (256KB).
  const int bid = blockIdx.x;          // 1024 blocks
  const int loc = bid >> 3;            // 0..127
  const int nIdx = loc & 15;           // 16 n-tiles
  const int mIdx = (bid & 7) * 8 + (loc >> 4);  // 64 m-tiles
  v16i acc[4][4] = {};
  gemm_core_r7<1024>(Aq, Bq, smem, acc, mIdx, nIdx);
  const float sw1 = scal[2];
  const int lane = threadIdx.x & 63;
  const int wave = threadIdx.x >> 6;
  const int m0 = mIdx * 256 + (wave & 1) * 128;
  const int n0 = nIdx * 256 + (wave >> 1) * 128;
  const int cn = lane & 31;
  const int h4 = (lane >> 5) << 2;
#pragma unroll
  for (int i = 0; i < 4; ++i) {
#pragma unroll
    for (int reg = 0; reg < 16; ++reg) {
      const int row = (reg & 3) + ((reg >> 2) << 3) + h4;  // C/D layout (m74/m101)
      const int m = m0 + i * 32 + row;
      const float rcp = 1.0f / (xscale[m] * sw1);
#pragma unroll
      for (int j = 0; j < 4; ++j) {
        const int n = n0 + j * 32 + cn;
        const float v = (float)acc[i][j][reg] * rcp + bias[n];
        const float hsw = v / (1.0f + __expf(-v));  // swish
        __hip_bfloat16 hb = __float2bfloat16(hsw);
        H[(size_t)m * 4096 + n] = *(const ushort*)&hb;
      }
    }
  }
}

// ---------------- GEMM2: C=hq@w2q^T, dequant+bias+mask+residual -> fp32 out ----------------
__global__ __launch_bounds__(256, 1) void gemm2_kernel(const int8_t* __restrict__ Aq,
                                                       const int8_t* __restrict__ Bq,
                                                       const float* __restrict__ hscale,
                                                       const float* __restrict__ scal,
                                                       const float* __restrict__ bias,
                                                       const float* __restrict__ x,
                                                       const float* __restrict__ mask,
                                                       float* __restrict__ out) {
  __shared__ __align__(16) int8_t smem[4 * 32768];  // 128 KB
  const int bid = blockIdx.x;          // 256 blocks
  const int loc = bid >> 3;            // 0..31
  const int nIdx = loc & 3;            // 4 n-tiles
  const int mIdx = (bid & 7) * 8 + (loc >> 2);  // 64 m-tiles
  v16i acc[4][4] = {};
  gemm_core_r7<4096>(Aq, Bq, smem, acc, mIdx, nIdx);
  const float sw2 = scal[3];
  const int lane = threadIdx.x & 63;
  const int wave = threadIdx.x >> 6;
  const int m0 = mIdx * 256 + (wave & 1) * 128;
  const int n0 = nIdx * 256 + (wave >> 1) * 128;
  const int cn = lane & 31;
  const int h4 = (lane >> 5) << 2;
#pragma unroll
  for (int i = 0; i < 4; ++i) {
#pragma unroll
    for (int reg = 0; reg < 16; ++reg) {
      const int row = (reg & 3) + ((reg >> 2) << 3) + h4;
      const int m = m0 + i * 32 + row;
      const float rcp = 1.0f / (hscale[m] * sw2);
      const float mk = 0.5f * mask[m];
#pragma unroll
      for (int j = 0; j < 4; ++j) {
        const int n = n0 + j * 32 + cn;
        const float v = (float)acc[i][j][reg] * rcp + bias[n];
        const size_t idx = (size_t)m * 1024 + n;
        out[idx] = x[idx] + mk * v;
      }
    }
  }
}

extern "C" void kernel_launch(void* const* d_in, const int* in_sizes, int n_in, void* d_out,
                              int out_size, void* d_ws, size_t ws_size, hipStream_t stream) {
  const float* x = (const float*)d_in[0];      // [8,2048,1024]
  const float* mask = (const float*)d_in[1];   // [8,2048,1]
  const float* gamma = (const float*)d_in[2];  // [1024]
  const float* beta = (const float*)d_in[3];   // [1024]
  const float* w1 = (const float*)d_in[4];     // [4096,1024]
  const float* b1 = (const float*)d_in[5];     // [4096]
  const float* w2 = (const float*)d_in[6];     // [1024,4096]
  const float* b2 = (const float*)d_in[7];     // [1024]
  const int* bits = (const int*)d_in[8];       // scalar
  float* out = (float*)d_out;

  char* ws = (char*)d_ws;
  int* wmax = (int*)ws;                              // slots [0],[1]
  float* scal = (float*)ws;                          // [2]=sw1 [3]=sw2 [4]=qb
  float* xscale = (float*)(ws + (1u << 20));         // 16384 f32
  float* hscale = (float*)(ws + (2u << 20));         // 16384 f32
  int8_t* w1q = (int8_t*)(ws + (4u << 20));          // 4 MB
  int8_t* w2q = (int8_t*)(ws + (8u << 20));          // 4 MB
  int8_t* xq = (int8_t*)(ws + (12u << 20));          // 16 MB
  int8_t* hq = (int8_t*)(ws + (28u << 20));          // 64 MB
  ushort* h = (ushort*)(ws + (size_t)(92u << 20));   // 128 MB bf16

  const int NW = 4096 * 1024;  // elements per weight matrix

  absmax_kernel<<<1024, 256, 0, stream>>>(w1, NW / 4, wmax + 0);
  absmax_kernel<<<1024, 256, 0, stream>>>(w2, NW / 4, wmax + 1);
  scales_kernel<<<1, 1, 0, stream>>>(wmax, bits, scal);
  wquant_kernel<<<NW / 1024, 256, 0, stream>>>(w1, scal, 0, w1q);
  wquant_kernel<<<NW / 1024, 256, 0, stream>>>(w2, scal, 1, w2q);
  ln_quant_kernel<<<16384, 256, 0, stream>>>(x, gamma, beta, xq, xscale);
  gemm1_kernel<<<1024, 256, 0, stream>>>(xq, w1q, xscale, scal, b1, h);
  hquant_kernel<<<16384, 256, 0, stream>>>(h, hq, hscale);
  gemm2_kernel<<<256, 256, 0, stream>>>(hq, w2q, hscale, scal, b2, x, mask, out);
}